// Round 2
// baseline (907.762 us; speedup 1.0000x reference)
//
#include <hip/hip_runtime.h>
#include <hip/hip_bf16.h>
#include <hip/hip_fp16.h>

#define D_ 1024
#define H_ 4096
#define NTOK 16384
#define MPAD 16512  // NTOK + 128 (padding so each 128-row tile is single-expert)

typedef __attribute__((ext_vector_type(8))) short bf16x8;
typedef __attribute__((ext_vector_type(4))) float f32x4;

static __device__ __forceinline__ unsigned short f2bf(float f) {
  union { float f; unsigned u; } x; x.f = f;
  unsigned u = x.u + 0x7fffu + ((x.u >> 16) & 1u);  // RNE
  return (unsigned short)(u >> 16);
}

static __device__ __forceinline__ void gld16(const void* g, void* l) {
  __builtin_amdgcn_global_load_lds(
      (const __attribute__((address_space(1))) unsigned int*)g,
      (__attribute__((address_space(3))) unsigned int*)l, 16, 0, 0);
}

// ---------------- transpose fp32 (R x C) -> bf16 (C x R) ----------------
__global__ __launch_bounds__(256) void transpose_bf16_kernel(
    const float* __restrict__ src, unsigned short* __restrict__ dst, int R, int C) {
  __shared__ float tile[32][33];
  const int c0 = blockIdx.x * 32, r0 = blockIdx.y * 32;
  const int tx = threadIdx.x & 31, ty = threadIdx.x >> 5;  // ty in [0,8)
#pragma unroll
  for (int i = 0; i < 32; i += 8)
    tile[ty + i][tx] = src[(size_t)(r0 + ty + i) * C + c0 + tx];
  __syncthreads();
#pragma unroll
  for (int i = 0; i < 32; i += 8)
    dst[(size_t)(c0 + ty + i) * R + r0 + tx] = f2bf(tile[tx][ty + i]);
}

// ---------------- stable compaction: rgb tokens first, expr at 128-aligned base
__global__ __launch_bounds__(256) void compact_kernel(
    const int* __restrict__ mask, int* __restrict__ perm, int* __restrict__ counts) {
  const int NT = 256, CH = NTOK / NT;  // 64 per thread
  __shared__ int c1[NT];
  __shared__ int e1[NT];
  __shared__ int s_total;
  const int t = threadIdx.x;
  const int base = t * CH;
  int cnt = 0;
  for (int i = 0; i < CH; ++i) cnt += (mask[base + i] != 0);
  c1[t] = cnt;
  for (int i = t; i < MPAD; i += NT) perm[i] = -1;  // gaps stay -1
  __syncthreads();
  if (t == 0) {
    int acc = 0;
    for (int i = 0; i < NT; ++i) { e1[i] = acc; acc += c1[i]; }
    s_total = acc;
    counts[0] = acc;          // # rgb tokens
    counts[1] = NTOK - acc;   // # expr tokens
  }
  __syncthreads();
  const int total1 = s_total;
  const int expr_base = ((total1 + 127) >> 7) << 7;
  int p1 = e1[t];
  int p0 = expr_base + (base - e1[t]);  // zeros before this chunk = base - e1[t]
  for (int i = 0; i < CH; ++i) {
    const int idx = base + i;
    if (mask[idx] != 0) perm[p1++] = idx; else perm[p0++] = idx;
  }
}

// ---------------- LayerNorm into compacted bf16 rows ----------------
__global__ __launch_bounds__(256) void ln_kernel(
    const float* __restrict__ x, const int* __restrict__ mask,
    const int* __restrict__ perm,
    const float* __restrict__ g_rgb, const float* __restrict__ b_rgb,
    const float* __restrict__ g_expr, const float* __restrict__ b_expr,
    unsigned short* __restrict__ xln) {
  const int i = blockIdx.x;
  const int t = perm[i];
  if (t < 0) return;
  const int tid = threadIdx.x;
  const float4 v = ((const float4*)(x + (size_t)t * D_))[tid];
  float s = v.x + v.y + v.z + v.w;
  float ss = v.x * v.x + v.y * v.y + v.z * v.z + v.w * v.w;
#pragma unroll
  for (int o = 32; o > 0; o >>= 1) {
    s += __shfl_xor(s, o, 64);
    ss += __shfl_xor(ss, o, 64);
  }
  __shared__ float red[8];
  const int wv = tid >> 6, ln = tid & 63;
  if (ln == 0) { red[wv] = s; red[4 + wv] = ss; }
  __syncthreads();
  s = red[0] + red[1] + red[2] + red[3];
  ss = red[4] + red[5] + red[6] + red[7];
  const float mu = s * (1.0f / D_);
  const float var = ss * (1.0f / D_) - mu * mu;
  const float rs = rsqrtf(var + 1e-5f);
  const bool rgb = mask[t] != 0;
  const float4 gv = ((const float4*)(rgb ? g_rgb : g_expr))[tid];
  const float4 bv = ((const float4*)(rgb ? b_rgb : b_expr))[tid];
  const unsigned short o0 = f2bf((v.x - mu) * rs * gv.x + bv.x);
  const unsigned short o1 = f2bf((v.y - mu) * rs * gv.y + bv.y);
  const unsigned short o2 = f2bf((v.z - mu) * rs * gv.z + bv.z);
  const unsigned short o3 = f2bf((v.w - mu) * rs * gv.w + bv.w);
  uint2 pk;
  pk.x = (unsigned)o0 | ((unsigned)o1 << 16);
  pk.y = (unsigned)o2 | ((unsigned)o3 << 16);
  *((uint2*)(xln + (size_t)i * D_ + tid * 4)) = pk;
}

// ---------------- m97-style 128x128x(BK=64) bf16 GEMM, B^T layout ----------------
// EP==0: C = gelu(A*W + bias) -> bf16 h[row*N + col]         (compact rows)
// EP==1: C = A*W + bias       -> fp32 out[perm[row]*N + col] (scatter, fp16-rounded)
template <int EP, int K, int N>
__global__ __launch_bounds__(256) void gemm_kernel(
    const unsigned short* __restrict__ A,       // MPAD x K, bf16 bits
    const unsigned short* __restrict__ Wt_rgb,  // N x K, bf16 bits
    const unsigned short* __restrict__ Wt_expr, // N x K
    const float* __restrict__ bias_rgb,
    const float* __restrict__ bias_expr,
    const int* __restrict__ counts,
    const int* __restrict__ perm,
    void* __restrict__ OutP) {
  constexpr int BM = 128, BN = 128, BK = 64;
  const int tid = threadIdx.x;
  const int n0 = blockIdx.x * BN;
  const int m0 = blockIdx.y * BM;
  const int cnt_rgb = counts[0];
  const unsigned short* Wt = (m0 < cnt_rgb) ? Wt_rgb : Wt_expr;
  const float* bias = (m0 < cnt_rgb) ? bias_rgb : bias_expr;

  __shared__ unsigned short As[BM * BK];  // [m][k], k contiguous (no pad: global_load_lds)
  __shared__ unsigned short Bs[BN * BK];  // [n][k]

  f32x4 acc[4][4] = {};

  const unsigned short* Abase = A + (size_t)m0 * K;
  const unsigned short* Bbase = Wt + (size_t)n0 * K;
  const int lane = tid & 63, wave = tid >> 6;
  const int wm = (wave & 1) * 64, wn = (wave >> 1) * 64;
  const int quad = lane >> 4, l16 = lane & 15;

  for (int k0 = 0; k0 < K; k0 += BK) {
#pragma unroll
    for (int it = 0; it < 4; ++it) {
      const int s = it * 256 + tid;
      const int row = s >> 3, ks = (s & 7) * 8;
      gld16(Abase + (size_t)row * K + k0 + ks, (char*)As + s * 16);
      gld16(Bbase + (size_t)row * K + k0 + ks, (char*)Bs + s * 16);
    }
    __syncthreads();
#pragma unroll
    for (int kk = 0; kk < BK; kk += 32) {
      const int lk = kk + quad * 8;
      bf16x8 a[4], b[4];
#pragma unroll
      for (int mi = 0; mi < 4; ++mi)
        a[mi] = *(const bf16x8*)(As + (wm + mi * 16 + l16) * BK + lk);
#pragma unroll
      for (int ni = 0; ni < 4; ++ni)
        b[ni] = *(const bf16x8*)(Bs + (wn + ni * 16 + l16) * BK + lk);
#pragma unroll
      for (int mi = 0; mi < 4; ++mi)
#pragma unroll
        for (int ni = 0; ni < 4; ++ni)
          acc[mi][ni] = __builtin_amdgcn_mfma_f32_16x16x32_bf16(a[mi], b[ni], acc[mi][ni], 0, 0, 0);
    }
    __syncthreads();
  }

  // epilogue: C/D layout col = lane&15, row = quad*4 + r  [m89/m91-verified]
#pragma unroll
  for (int ni = 0; ni < 4; ++ni) {
    const int col = n0 + wn + ni * 16 + l16;
    const float bv = bias[col];
#pragma unroll
    for (int mi = 0; mi < 4; ++mi) {
#pragma unroll
      for (int r = 0; r < 4; ++r) {
        const int row = m0 + wm + mi * 16 + quad * 4 + r;
        const int p = perm[row];
        if (p < 0) continue;
        float v = acc[mi][ni][r] + bv;
        if (EP == 0) {
          v = 0.5f * v * (1.0f + erff(v * 0.70710678118654752f));  // exact gelu
          ((unsigned short*)OutP)[(size_t)row * N + col] = f2bf(v);
        } else {
          // reference output is z.astype(float16); d_out is an fp32 buffer
          // (harness: "bfloat16 -> __hip_bfloat16*, else float*")
          ((float*)OutP)[(size_t)p * N + col] = __half2float(__float2half_rn(v));
        }
      }
    }
  }
}

extern "C" void kernel_launch(void* const* d_in, const int* in_sizes, int n_in,
                              void* d_out, int out_size, void* d_ws, size_t ws_size,
                              hipStream_t stream) {
  const float* x       = (const float*)d_in[0];
  const int*   mask    = (const int*)d_in[1];
  const float* g_rgb   = (const float*)d_in[2];
  const float* b_rgb   = (const float*)d_in[3];
  const float* w1_rgb  = (const float*)d_in[4];
  const float* b1_rgb  = (const float*)d_in[5];
  const float* w2_rgb  = (const float*)d_in[6];
  const float* b2_rgb  = (const float*)d_in[7];
  const float* g_expr  = (const float*)d_in[8];
  const float* b_expr  = (const float*)d_in[9];
  const float* w1_expr = (const float*)d_in[10];
  const float* b1_expr = (const float*)d_in[11];
  const float* w2_expr = (const float*)d_in[12];
  const float* b2_expr = (const float*)d_in[13];

  char* w = (char*)d_ws;
  int* counts               = (int*)(w + 0);
  int* perm                 = (int*)(w + 256);
  unsigned short* w1t_rgb   = (unsigned short*)(w + 66560);
  unsigned short* w1t_expr  = (unsigned short*)(w + 8455168);
  unsigned short* w2t_rgb   = (unsigned short*)(w + 16843776);
  unsigned short* w2t_expr  = (unsigned short*)(w + 25232384);
  unsigned short* xln       = (unsigned short*)(w + 33620992);  // MPAD x 1024 bf16
  unsigned short* h         = (unsigned short*)(w + 67437568);  // MPAD x 4096 bf16
  // total ws use: 202,703,872 bytes

  // 1) weight transpose+convert: W (KxN fp32) -> Wt (NxK bf16)
  transpose_bf16_kernel<<<dim3(H_ / 32, D_ / 32), 256, 0, stream>>>(w1_rgb, w1t_rgb, D_, H_);
  transpose_bf16_kernel<<<dim3(H_ / 32, D_ / 32), 256, 0, stream>>>(w1_expr, w1t_expr, D_, H_);
  transpose_bf16_kernel<<<dim3(D_ / 32, H_ / 32), 256, 0, stream>>>(w2_rgb, w2t_rgb, H_, D_);
  transpose_bf16_kernel<<<dim3(D_ / 32, H_ / 32), 256, 0, stream>>>(w2_expr, w2t_expr, H_, D_);

  // 2) stable expert compaction
  compact_kernel<<<1, 256, 0, stream>>>(mask, perm, counts);

  // 3) LayerNorm into compacted rows
  ln_kernel<<<MPAD, 256, 0, stream>>>(x, mask, perm, g_rgb, b_rgb, g_expr, b_expr, xln);

  // 4) h = gelu(xln @ w1 + b1)   (M=MPAD, K=1024, N=4096)
  gemm_kernel<0, D_, H_><<<dim3(H_ / 128, MPAD / 128), 256, 0, stream>>>(
      xln, w1t_rgb, w1t_expr, b1_rgb, b1_expr, counts, perm, h);

  // 5) out[tok] = h @ w2 + b2    (M=MPAD, K=4096, N=1024), scatter via perm, fp32 out
  gemm_kernel<1, H_, D_><<<dim3(D_ / 128, MPAD / 128), 256, 0, stream>>>(
      h, w2t_rgb, w2t_expr, b2_rgb, b2_expr, counts, perm, d_out);
}

// Round 3
// 748.855 us; speedup vs baseline: 1.2122x; 1.2122x over previous
//
#include <hip/hip_runtime.h>
#include <hip/hip_bf16.h>
#include <hip/hip_fp16.h>

#define D_ 1024
#define H_ 4096
#define NTOK 16384
#define MPAD 16512  // NTOK + 128 (padding so each 128-row tile is single-expert)

typedef __attribute__((ext_vector_type(8))) short bf16x8;
typedef __attribute__((ext_vector_type(4))) float f32x4;

static __device__ __forceinline__ unsigned short f2bf(float f) {
  union { float f; unsigned u; } x; x.f = f;
  unsigned u = x.u + 0x7fffu + ((x.u >> 16) & 1u);  // RNE
  return (unsigned short)(u >> 16);
}

static __device__ __forceinline__ void gld16(const void* g, void* l) {
  __builtin_amdgcn_global_load_lds(
      (const __attribute__((address_space(1))) unsigned int*)g,
      (__attribute__((address_space(3))) unsigned int*)l, 16, 0, 0);
}

// ---------------- transpose fp32 (R x C) -> bf16 (C x R) ----------------
__global__ __launch_bounds__(256) void transpose_bf16_kernel(
    const float* __restrict__ src, unsigned short* __restrict__ dst, int R, int C) {
  __shared__ float tile[32][33];
  const int c0 = blockIdx.x * 32, r0 = blockIdx.y * 32;
  const int tx = threadIdx.x & 31, ty = threadIdx.x >> 5;  // ty in [0,8)
#pragma unroll
  for (int i = 0; i < 32; i += 8)
    tile[ty + i][tx] = src[(size_t)(r0 + ty + i) * C + c0 + tx];
  __syncthreads();
#pragma unroll
  for (int i = 0; i < 32; i += 8)
    dst[(size_t)(c0 + ty + i) * R + r0 + tx] = f2bf(tile[tx][ty + i]);
}

// ---------------- stable compaction: rgb tokens first, expr at 128-aligned base
__global__ __launch_bounds__(256) void compact_kernel(
    const int* __restrict__ mask, int* __restrict__ perm, int* __restrict__ counts) {
  const int NT = 256, CH = NTOK / NT;  // 64 per thread
  __shared__ int c1[NT];
  __shared__ int e1[NT];
  __shared__ int s_total;
  const int t = threadIdx.x;
  const int base = t * CH;
  int cnt = 0;
  for (int i = 0; i < CH; ++i) cnt += (mask[base + i] != 0);
  c1[t] = cnt;
  for (int i = t; i < MPAD; i += NT) perm[i] = -1;  // gaps stay -1
  __syncthreads();
  if (t == 0) {
    int acc = 0;
    for (int i = 0; i < NT; ++i) { e1[i] = acc; acc += c1[i]; }
    s_total = acc;
    counts[0] = acc;          // # rgb tokens
    counts[1] = NTOK - acc;   // # expr tokens
  }
  __syncthreads();
  const int total1 = s_total;
  const int expr_base = ((total1 + 127) >> 7) << 7;
  int p1 = e1[t];
  int p0 = expr_base + (base - e1[t]);  // zeros before this chunk = base - e1[t]
  for (int i = 0; i < CH; ++i) {
    const int idx = base + i;
    if (mask[idx] != 0) perm[p1++] = idx; else perm[p0++] = idx;
  }
}

// ---------------- LayerNorm into compacted bf16 rows ----------------
__global__ __launch_bounds__(256) void ln_kernel(
    const float* __restrict__ x, const int* __restrict__ mask,
    const int* __restrict__ perm,
    const float* __restrict__ g_rgb, const float* __restrict__ b_rgb,
    const float* __restrict__ g_expr, const float* __restrict__ b_expr,
    unsigned short* __restrict__ xln) {
  const int i = blockIdx.x;
  const int t = perm[i];
  if (t < 0) return;
  const int tid = threadIdx.x;
  const float4 v = ((const float4*)(x + (size_t)t * D_))[tid];
  float s = v.x + v.y + v.z + v.w;
  float ss = v.x * v.x + v.y * v.y + v.z * v.z + v.w * v.w;
#pragma unroll
  for (int o = 32; o > 0; o >>= 1) {
    s += __shfl_xor(s, o, 64);
    ss += __shfl_xor(ss, o, 64);
  }
  __shared__ float red[8];
  const int wv = tid >> 6, ln = tid & 63;
  if (ln == 0) { red[wv] = s; red[4 + wv] = ss; }
  __syncthreads();
  s = red[0] + red[1] + red[2] + red[3];
  ss = red[4] + red[5] + red[6] + red[7];
  const float mu = s * (1.0f / D_);
  const float var = ss * (1.0f / D_) - mu * mu;
  const float rs = rsqrtf(var + 1e-5f);
  const bool rgb = mask[t] != 0;
  const float4 gv = ((const float4*)(rgb ? g_rgb : g_expr))[tid];
  const float4 bv = ((const float4*)(rgb ? b_rgb : b_expr))[tid];
  const unsigned short o0 = f2bf((v.x - mu) * rs * gv.x + bv.x);
  const unsigned short o1 = f2bf((v.y - mu) * rs * gv.y + bv.y);
  const unsigned short o2 = f2bf((v.z - mu) * rs * gv.z + bv.z);
  const unsigned short o3 = f2bf((v.w - mu) * rs * gv.w + bv.w);
  uint2 pk;
  pk.x = (unsigned)o0 | ((unsigned)o1 << 16);
  pk.y = (unsigned)o2 | ((unsigned)o3 << 16);
  *((uint2*)(xln + (size_t)i * D_ + tid * 4)) = pk;
}

// ---------------- m97-style 128x128x(BK=64) bf16 GEMM, B^T layout ----------------
// LDS layout is XOR-swizzled at 16B-chunk granularity: LDS chunk (row, c)
// holds global k-chunk (c ^ (row&7)). Staging permutes the per-lane global
// source (global_load_lds dest is fixed at base+lane*16); reads address
// row*BK + ((c ^ row)&7)*8. This spreads a quad-group's 16 rows across all
// 32 banks (2 lanes/bank = free) instead of one 4-bank group (was 5.07e7
// SQ_LDS_BANK_CONFLICT per dispatch).
// EP==0: C = gelu(A*W + bias) -> bf16 h[row*N + col]         (compact rows)
// EP==1: C = A*W + bias       -> fp32 out[perm[row]*N + col] (scatter, fp16-rounded)
template <int EP, int K, int N>
__global__ __launch_bounds__(256) void gemm_kernel(
    const unsigned short* __restrict__ A,       // MPAD x K, bf16 bits
    const unsigned short* __restrict__ Wt_rgb,  // N x K, bf16 bits
    const unsigned short* __restrict__ Wt_expr, // N x K
    const float* __restrict__ bias_rgb,
    const float* __restrict__ bias_expr,
    const int* __restrict__ counts,
    const int* __restrict__ perm,
    void* __restrict__ OutP) {
  constexpr int BM = 128, BN = 128, BK = 64;
  const int tid = threadIdx.x;
  const int n0 = blockIdx.x * BN;
  const int m0 = blockIdx.y * BM;
  const int cnt_rgb = counts[0];
  const unsigned short* Wt = (m0 < cnt_rgb) ? Wt_rgb : Wt_expr;
  const float* bias = (m0 < cnt_rgb) ? bias_rgb : bias_expr;

  __shared__ unsigned short As[BM * BK];  // swizzled [m][k]
  __shared__ unsigned short Bs[BN * BK];  // swizzled [n][k]

  f32x4 acc[4][4] = {};

  const unsigned short* Abase = A + (size_t)m0 * K;
  const unsigned short* Bbase = Wt + (size_t)n0 * K;
  const int lane = tid & 63, wave = tid >> 6;
  const int wm = (wave & 1) * 64, wn = (wave >> 1) * 64;
  const int quad = lane >> 4, l16 = lane & 15;

  for (int k0 = 0; k0 < K; k0 += BK) {
#pragma unroll
    for (int it = 0; it < 4; ++it) {
      const int s = it * 256 + tid;
      const int row = s >> 3;
      const int ks = ((s ^ row) & 7) * 8;  // chunk col (s&7) holds global chunk (s^row)&7
      gld16(Abase + (size_t)row * K + k0 + ks, (char*)As + s * 16);
      gld16(Bbase + (size_t)row * K + k0 + ks, (char*)Bs + s * 16);
    }
    __syncthreads();
#pragma unroll
    for (int kk = 0; kk < BK; kk += 32) {
      const int cbase = (kk >> 3) + quad;  // global k-chunk index 0..7
      bf16x8 a[4], b[4];
#pragma unroll
      for (int mi = 0; mi < 4; ++mi) {
        const int row = wm + mi * 16 + l16;
        a[mi] = *(const bf16x8*)(As + row * BK + (((cbase ^ row) & 7) << 3));
      }
#pragma unroll
      for (int ni = 0; ni < 4; ++ni) {
        const int row = wn + ni * 16 + l16;
        b[ni] = *(const bf16x8*)(Bs + row * BK + (((cbase ^ row) & 7) << 3));
      }
#pragma unroll
      for (int mi = 0; mi < 4; ++mi)
#pragma unroll
        for (int ni = 0; ni < 4; ++ni)
          acc[mi][ni] = __builtin_amdgcn_mfma_f32_16x16x32_bf16(a[mi], b[ni], acc[mi][ni], 0, 0, 0);
    }
    __syncthreads();
  }

  // epilogue: C/D layout col = lane&15, row = quad*4 + r  [m89/m91-verified]
  float bv[4];
#pragma unroll
  for (int ni = 0; ni < 4; ++ni) bv[ni] = bias[n0 + wn + ni * 16 + l16];

#pragma unroll
  for (int mi = 0; mi < 4; ++mi) {
#pragma unroll
    for (int r = 0; r < 4; ++r) {
      const int row = m0 + wm + mi * 16 + quad * 4 + r;
      if (EP == 0) {
        // gap rows read poisoned-but-finite xln; store unconditionally (never scattered)
        unsigned short* orow = (unsigned short*)OutP + (size_t)row * N + n0 + wn + l16;
#pragma unroll
        for (int ni = 0; ni < 4; ++ni) {
          float v = acc[mi][ni][r] + bv[ni];
          v = 0.5f * v * (1.0f + erff(v * 0.70710678118654752f));  // exact gelu
          orow[ni * 16] = f2bf(v);
        }
      } else {
        const int p = perm[row];
        if (p < 0) continue;
        // reference output is z.astype(float16); d_out is an fp32 buffer
        float* orow = (float*)OutP + (size_t)p * N + n0 + wn + l16;
#pragma unroll
        for (int ni = 0; ni < 4; ++ni) {
          float v = acc[mi][ni][r] + bv[ni];
          orow[ni * 16] = __half2float(__float2half_rn(v));
        }
      }
    }
  }
}

extern "C" void kernel_launch(void* const* d_in, const int* in_sizes, int n_in,
                              void* d_out, int out_size, void* d_ws, size_t ws_size,
                              hipStream_t stream) {
  const float* x       = (const float*)d_in[0];
  const int*   mask    = (const int*)d_in[1];
  const float* g_rgb   = (const float*)d_in[2];
  const float* b_rgb   = (const float*)d_in[3];
  const float* w1_rgb  = (const float*)d_in[4];
  const float* b1_rgb  = (const float*)d_in[5];
  const float* w2_rgb  = (const float*)d_in[6];
  const float* b2_rgb  = (const float*)d_in[7];
  const float* g_expr  = (const float*)d_in[8];
  const float* b_expr  = (const float*)d_in[9];
  const float* w1_expr = (const float*)d_in[10];
  const float* b1_expr = (const float*)d_in[11];
  const float* w2_expr = (const float*)d_in[12];
  const float* b2_expr = (const float*)d_in[13];

  char* w = (char*)d_ws;
  int* counts               = (int*)(w + 0);
  int* perm                 = (int*)(w + 256);
  unsigned short* w1t_rgb   = (unsigned short*)(w + 66560);
  unsigned short* w1t_expr  = (unsigned short*)(w + 8455168);
  unsigned short* w2t_rgb   = (unsigned short*)(w + 16843776);
  unsigned short* w2t_expr  = (unsigned short*)(w + 25232384);
  unsigned short* xln       = (unsigned short*)(w + 33620992);  // MPAD x 1024 bf16
  unsigned short* h         = (unsigned short*)(w + 67437568);  // MPAD x 4096 bf16
  // total ws use: 202,703,872 bytes

  // 1) weight transpose+convert: W (KxN fp32) -> Wt (NxK bf16)
  transpose_bf16_kernel<<<dim3(H_ / 32, D_ / 32), 256, 0, stream>>>(w1_rgb, w1t_rgb, D_, H_);
  transpose_bf16_kernel<<<dim3(H_ / 32, D_ / 32), 256, 0, stream>>>(w1_expr, w1t_expr, D_, H_);
  transpose_bf16_kernel<<<dim3(D_ / 32, H_ / 32), 256, 0, stream>>>(w2_rgb, w2t_rgb, H_, D_);
  transpose_bf16_kernel<<<dim3(D_ / 32, H_ / 32), 256, 0, stream>>>(w2_expr, w2t_expr, H_, D_);

  // 2) stable expert compaction
  compact_kernel<<<1, 256, 0, stream>>>(mask, perm, counts);

  // 3) LayerNorm into compacted rows
  ln_kernel<<<MPAD, 256, 0, stream>>>(x, mask, perm, g_rgb, b_rgb, g_expr, b_expr, xln);

  // 4) h = gelu(xln @ w1 + b1)   (M=MPAD, K=1024, N=4096)
  gemm_kernel<0, D_, H_><<<dim3(H_ / 128, MPAD / 128), 256, 0, stream>>>(
      xln, w1t_rgb, w1t_expr, b1_rgb, b1_expr, counts, perm, h);

  // 5) out[tok] = h @ w2 + b2    (M=MPAD, K=4096, N=1024), scatter via perm, fp32 out
  gemm_kernel<1, H_, D_><<<dim3(D_ / 128, MPAD / 128), 256, 0, stream>>>(
      h, w2t_rgb, w2t_expr, b2_rgb, b2_expr, counts, perm, d_out);
}

// Round 4
// 700.341 us; speedup vs baseline: 1.2962x; 1.0693x over previous
//
#include <hip/hip_runtime.h>
#include <hip/hip_bf16.h>
#include <hip/hip_fp16.h>

#define D_ 1024
#define H_ 4096
#define NTOK 16384
#define MPAD 16512  // NTOK + 128 (padding so each 128-row tile is single-expert)

typedef __attribute__((ext_vector_type(8))) short bf16x8;
typedef __attribute__((ext_vector_type(4))) float f32x4;

static __device__ __forceinline__ unsigned short f2bf(float f) {
  union { float f; unsigned u; } x; x.f = f;
  unsigned u = x.u + 0x7fffu + ((x.u >> 16) & 1u);  // RNE
  return (unsigned short)(u >> 16);
}

static __device__ __forceinline__ void gld16(const void* g, void* l) {
  __builtin_amdgcn_global_load_lds(
      (const __attribute__((address_space(1))) unsigned int*)g,
      (__attribute__((address_space(3))) unsigned int*)l, 16, 0, 0);
}

// ---------------- transpose fp32 (R x C) -> bf16 (C x R) ----------------
__global__ __launch_bounds__(256) void transpose_bf16_kernel(
    const float* __restrict__ src, unsigned short* __restrict__ dst, int R, int C) {
  __shared__ float tile[32][33];
  const int c0 = blockIdx.x * 32, r0 = blockIdx.y * 32;
  const int tx = threadIdx.x & 31, ty = threadIdx.x >> 5;  // ty in [0,8)
#pragma unroll
  for (int i = 0; i < 32; i += 8)
    tile[ty + i][tx] = src[(size_t)(r0 + ty + i) * C + c0 + tx];
  __syncthreads();
#pragma unroll
  for (int i = 0; i < 32; i += 8)
    dst[(size_t)(c0 + ty + i) * R + r0 + tx] = f2bf(tile[tx][ty + i]);
}

// ---------------- stable compaction: rgb tokens first, expr at 128-aligned base
// Coalesced mask read into LDS + shfl-based parallel scan (old version did
// stride-64 uncoalesced global loads + serial 256-entry scan: ~80 us).
__global__ __launch_bounds__(256) void compact_kernel(
    const int* __restrict__ mask, int* __restrict__ perm, int* __restrict__ counts) {
  const int NT = 256, CH = NTOK / NT;  // 64 per thread
  __shared__ int sm[NTOK];
  __shared__ int wsum[4];
  const int t = threadIdx.x;
  const int ln = t & 63, wv = t >> 6;
  for (int i = t; i < NTOK; i += NT) sm[i] = mask[i];       // coalesced
  for (int i = t; i < MPAD; i += NT) perm[i] = -1;          // gaps stay -1
  __syncthreads();
  const int base = t * CH;
  int cnt = 0;
  for (int i = 0; i < CH; ++i) cnt += (sm[base + i] != 0);
  // inclusive scan within wave
  int sc = cnt;
#pragma unroll
  for (int o = 1; o < 64; o <<= 1) {
    int u = __shfl_up(sc, o, 64);
    if (ln >= o) sc += u;
  }
  if (ln == 63) wsum[wv] = sc;
  __syncthreads();
  int woff = 0;
#pragma unroll
  for (int j = 0; j < 4; ++j) woff += (j < wv) ? wsum[j] : 0;
  const int total1 = wsum[0] + wsum[1] + wsum[2] + wsum[3];
  if (t == 0) { counts[0] = total1; counts[1] = NTOK - total1; }
  const int excl = woff + sc - cnt;  // rgb tokens before this chunk
  const int expr_base = ((total1 + 127) >> 7) << 7;
  int p1 = excl;
  int p0 = expr_base + (base - excl);
  for (int i = 0; i < CH; ++i) {
    const int idx = base + i;
    if (sm[idx] != 0) perm[p1++] = idx; else perm[p0++] = idx;
  }
}

// ---------------- LayerNorm into compacted bf16 rows ----------------
__global__ __launch_bounds__(256) void ln_kernel(
    const float* __restrict__ x, const int* __restrict__ mask,
    const int* __restrict__ perm,
    const float* __restrict__ g_rgb, const float* __restrict__ b_rgb,
    const float* __restrict__ g_expr, const float* __restrict__ b_expr,
    unsigned short* __restrict__ xln) {
  const int i = blockIdx.x;
  const int t = perm[i];
  if (t < 0) return;
  const int tid = threadIdx.x;
  const float4 v = ((const float4*)(x + (size_t)t * D_))[tid];
  float s = v.x + v.y + v.z + v.w;
  float ss = v.x * v.x + v.y * v.y + v.z * v.z + v.w * v.w;
#pragma unroll
  for (int o = 32; o > 0; o >>= 1) {
    s += __shfl_xor(s, o, 64);
    ss += __shfl_xor(ss, o, 64);
  }
  __shared__ float red[8];
  const int wv = tid >> 6, ln = tid & 63;
  if (ln == 0) { red[wv] = s; red[4 + wv] = ss; }
  __syncthreads();
  s = red[0] + red[1] + red[2] + red[3];
  ss = red[4] + red[5] + red[6] + red[7];
  const float mu = s * (1.0f / D_);
  const float var = ss * (1.0f / D_) - mu * mu;
  const float rs = rsqrtf(var + 1e-5f);
  const bool rgb = mask[t] != 0;
  const float4 gv = ((const float4*)(rgb ? g_rgb : g_expr))[tid];
  const float4 bv = ((const float4*)(rgb ? b_rgb : b_expr))[tid];
  const unsigned short o0 = f2bf((v.x - mu) * rs * gv.x + bv.x);
  const unsigned short o1 = f2bf((v.y - mu) * rs * gv.y + bv.y);
  const unsigned short o2 = f2bf((v.z - mu) * rs * gv.z + bv.z);
  const unsigned short o3 = f2bf((v.w - mu) * rs * gv.w + bv.w);
  uint2 pk;
  pk.x = (unsigned)o0 | ((unsigned)o1 << 16);
  pk.y = (unsigned)o2 | ((unsigned)o3 << 16);
  *((uint2*)(xln + (size_t)i * D_ + tid * 4)) = pk;
}

// ---------------- m97-style 128x128x(BK=64) bf16 GEMM, B^T layout ----------------
// LDS XOR-swizzled at 16B-chunk granularity (round 3: bank conflicts -> 0).
// Block->tile mapping is XCD-compact: xcd = id&7 owns a contiguous m-band x
// all n-tiles, n-fastest. All ~G/8 blocks of an XCD progress the k-loop in
// near-lockstep, so per-k-step working set (~0.5 MB) fits the XCD's 4 MB L2:
// A-chunks shared by NT blocks within the XCD instead of 0 (round 3 had
// XCD = n-tile => zero intra-XCD A reuse => 545 MB HBM fetch).
// EP==0: C = gelu(A*W + bias) -> bf16 h[row*N + col]         (compact rows)
// EP==1: C = A*W + bias       -> fp32 out[perm[row]*N + col] (scatter, fp16-rounded)
template <int EP, int K, int N>
__global__ __launch_bounds__(256) void gemm_kernel(
    const unsigned short* __restrict__ A,       // MPAD x K, bf16 bits
    const unsigned short* __restrict__ Wt_rgb,  // N x K, bf16 bits
    const unsigned short* __restrict__ Wt_expr, // N x K
    const float* __restrict__ bias_rgb,
    const float* __restrict__ bias_expr,
    const int* __restrict__ counts,
    const int* __restrict__ perm,
    void* __restrict__ OutP) {
  constexpr int BM = 128, BN = 128, BK = 64;
  constexpr int MT = MPAD / BM;   // 129
  constexpr int NT = N / BN;      // 32 (gemm1) / 8 (gemm2)
  const int tid = threadIdx.x;
  const int id = blockIdx.x;
  const int xcd = id & 7;
  const int slot = id >> 3;
  const int p = xcd * ((MT * NT) / 8) + slot;
  const int m0 = (p / NT) * BM;
  const int n0 = (p % NT) * BN;
  const int cnt_rgb = counts[0];
  const unsigned short* Wt = (m0 < cnt_rgb) ? Wt_rgb : Wt_expr;
  const float* bias = (m0 < cnt_rgb) ? bias_rgb : bias_expr;

  __shared__ unsigned short As[BM * BK];  // swizzled [m][k]
  __shared__ unsigned short Bs[BN * BK];  // swizzled [n][k]

  f32x4 acc[4][4] = {};

  const unsigned short* Abase = A + (size_t)m0 * K;
  const unsigned short* Bbase = Wt + (size_t)n0 * K;
  const int lane = tid & 63, wave = tid >> 6;
  const int wm = (wave & 1) * 64, wn = (wave >> 1) * 64;
  const int quad = lane >> 4, l16 = lane & 15;

  for (int k0 = 0; k0 < K; k0 += BK) {
#pragma unroll
    for (int it = 0; it < 4; ++it) {
      const int s = it * 256 + tid;
      const int row = s >> 3;
      const int ks = ((s ^ row) & 7) * 8;  // chunk col (s&7) holds global chunk (s^row)&7
      gld16(Abase + (size_t)row * K + k0 + ks, (char*)As + s * 16);
      gld16(Bbase + (size_t)row * K + k0 + ks, (char*)Bs + s * 16);
    }
    __syncthreads();
#pragma unroll
    for (int kk = 0; kk < BK; kk += 32) {
      const int cbase = (kk >> 3) + quad;  // global k-chunk index 0..7
      bf16x8 a[4], b[4];
#pragma unroll
      for (int mi = 0; mi < 4; ++mi) {
        const int row = wm + mi * 16 + l16;
        a[mi] = *(const bf16x8*)(As + row * BK + (((cbase ^ row) & 7) << 3));
      }
#pragma unroll
      for (int ni = 0; ni < 4; ++ni) {
        const int row = wn + ni * 16 + l16;
        b[ni] = *(const bf16x8*)(Bs + row * BK + (((cbase ^ row) & 7) << 3));
      }
#pragma unroll
      for (int mi = 0; mi < 4; ++mi)
#pragma unroll
        for (int ni = 0; ni < 4; ++ni)
          acc[mi][ni] = __builtin_amdgcn_mfma_f32_16x16x32_bf16(a[mi], b[ni], acc[mi][ni], 0, 0, 0);
    }
    __syncthreads();
  }

  // epilogue: C/D layout col = lane&15, row = quad*4 + r  [m89/m91-verified]
  float bv[4];
#pragma unroll
  for (int ni = 0; ni < 4; ++ni) bv[ni] = bias[n0 + wn + ni * 16 + l16];

#pragma unroll
  for (int mi = 0; mi < 4; ++mi) {
#pragma unroll
    for (int r = 0; r < 4; ++r) {
      const int row = m0 + wm + mi * 16 + quad * 4 + r;
      if (EP == 0) {
        // gap rows read poisoned-but-finite xln; store unconditionally (never scattered)
        unsigned short* orow = (unsigned short*)OutP + (size_t)row * N + n0 + wn + l16;
#pragma unroll
        for (int ni = 0; ni < 4; ++ni) {
          float v = acc[mi][ni][r] + bv[ni];
          v = 0.5f * v * (1.0f + erff(v * 0.70710678118654752f));  // exact gelu
          orow[ni * 16] = f2bf(v);
        }
      } else {
        const int p2 = perm[row];
        if (p2 < 0) continue;
        // reference output is z.astype(float16); d_out is an fp32 buffer
        float* orow = (float*)OutP + (size_t)p2 * N + n0 + wn + l16;
#pragma unroll
        for (int ni = 0; ni < 4; ++ni) {
          float v = acc[mi][ni][r] + bv[ni];
          orow[ni * 16] = __half2float(__float2half_rn(v));
        }
      }
    }
  }
}

extern "C" void kernel_launch(void* const* d_in, const int* in_sizes, int n_in,
                              void* d_out, int out_size, void* d_ws, size_t ws_size,
                              hipStream_t stream) {
  const float* x       = (const float*)d_in[0];
  const int*   mask    = (const int*)d_in[1];
  const float* g_rgb   = (const float*)d_in[2];
  const float* b_rgb   = (const float*)d_in[3];
  const float* w1_rgb  = (const float*)d_in[4];
  const float* b1_rgb  = (const float*)d_in[5];
  const float* w2_rgb  = (const float*)d_in[6];
  const float* b2_rgb  = (const float*)d_in[7];
  const float* g_expr  = (const float*)d_in[8];
  const float* b_expr  = (const float*)d_in[9];
  const float* w1_expr = (const float*)d_in[10];
  const float* b1_expr = (const float*)d_in[11];
  const float* w2_expr = (const float*)d_in[12];
  const float* b2_expr = (const float*)d_in[13];

  char* w = (char*)d_ws;
  int* counts               = (int*)(w + 0);
  int* perm                 = (int*)(w + 256);
  unsigned short* w1t_rgb   = (unsigned short*)(w + 66560);
  unsigned short* w1t_expr  = (unsigned short*)(w + 8455168);
  unsigned short* w2t_rgb   = (unsigned short*)(w + 16843776);
  unsigned short* w2t_expr  = (unsigned short*)(w + 25232384);
  unsigned short* xln       = (unsigned short*)(w + 33620992);  // MPAD x 1024 bf16
  unsigned short* h         = (unsigned short*)(w + 67437568);  // MPAD x 4096 bf16
  // total ws use: 202,703,872 bytes

  // 1) weight transpose+convert: W (KxN fp32) -> Wt (NxK bf16)
  transpose_bf16_kernel<<<dim3(H_ / 32, D_ / 32), 256, 0, stream>>>(w1_rgb, w1t_rgb, D_, H_);
  transpose_bf16_kernel<<<dim3(H_ / 32, D_ / 32), 256, 0, stream>>>(w1_expr, w1t_expr, D_, H_);
  transpose_bf16_kernel<<<dim3(D_ / 32, H_ / 32), 256, 0, stream>>>(w2_rgb, w2t_rgb, H_, D_);
  transpose_bf16_kernel<<<dim3(D_ / 32, H_ / 32), 256, 0, stream>>>(w2_expr, w2t_expr, H_, D_);

  // 2) stable expert compaction
  compact_kernel<<<1, 256, 0, stream>>>(mask, perm, counts);

  // 3) LayerNorm into compacted rows
  ln_kernel<<<MPAD, 256, 0, stream>>>(x, mask, perm, g_rgb, b_rgb, g_expr, b_expr, xln);

  // 4) h = gelu(xln @ w1 + b1)   (M=MPAD, K=1024, N=4096)
  gemm_kernel<0, D_, H_><<<dim3((H_ / 128) * (MPAD / 128)), 256, 0, stream>>>(
      xln, w1t_rgb, w1t_expr, b1_rgb, b1_expr, counts, perm, h);

  // 5) out[tok] = h @ w2 + b2    (M=MPAD, K=4096, N=1024), scatter via perm, fp32 out
  gemm_kernel<1, H_, D_><<<dim3((D_ / 128) * (MPAD / 128)), 256, 0, stream>>>(
      h, w2t_rgb, w2t_expr, b2_rgb, b2_expr, counts, perm, d_out);
}

// Round 5
// 600.239 us; speedup vs baseline: 1.5123x; 1.1668x over previous
//
#include <hip/hip_runtime.h>
#include <hip/hip_bf16.h>
#include <hip/hip_fp16.h>

#define D_ 1024
#define H_ 4096
#define NTOK 16384
#define MPAD 16512  // NTOK + 128 (padding so each 128-row tile is single-expert)

typedef __attribute__((ext_vector_type(8))) short bf16x8;
typedef __attribute__((ext_vector_type(4))) float f32x4;

static __device__ __forceinline__ unsigned short f2bf(float f) {
  union { float f; unsigned u; } x; x.f = f;
  unsigned u = x.u + 0x7fffu + ((x.u >> 16) & 1u);  // RNE
  return (unsigned short)(u >> 16);
}

static __device__ __forceinline__ void gld16(const void* g, void* l) {
  __builtin_amdgcn_global_load_lds(
      (const __attribute__((address_space(1))) unsigned int*)g,
      (__attribute__((address_space(3))) unsigned int*)l, 16, 0, 0);
}

// tanh-form gelu reduced to x*sigmoid(2c(x+0.044715x^3)); |err vs exact| ~1e-3
static __device__ __forceinline__ float gelu_fast(float x) {
  const float z = x * (1.5957691216f + 0.0713548163f * x * x);
  return x * __builtin_amdgcn_rcpf(1.0f + __expf(-z));
}

// ---------------- merged transpose fp32 (R x C) -> bf16 (C x R), 4 matrices ----
__global__ __launch_bounds__(256) void transpose4_kernel(
    const float* __restrict__ w1r, const float* __restrict__ w1e,
    const float* __restrict__ w2r, const float* __restrict__ w2e,
    unsigned short* __restrict__ o1r, unsigned short* __restrict__ o1e,
    unsigned short* __restrict__ o2r, unsigned short* __restrict__ o2e) {
  __shared__ float tile[32][33];
  const int t = blockIdx.x;  // 4 x 4096 tiles of 32x32
  const float* src; unsigned short* dst; int R, C, tl;
  if (t < 4096)       { src = w1r; dst = o1r; R = D_; C = H_; tl = t; }
  else if (t < 8192)  { src = w1e; dst = o1e; R = D_; C = H_; tl = t - 4096; }
  else if (t < 12288) { src = w2r; dst = o2r; R = H_; C = D_; tl = t - 8192; }
  else                { src = w2e; dst = o2e; R = H_; C = D_; tl = t - 12288; }
  const int tc = C >> 5;
  const int r0 = (tl / tc) * 32, c0 = (tl % tc) * 32;
  const int tx = threadIdx.x & 31, ty = threadIdx.x >> 5;  // ty in [0,8)
#pragma unroll
  for (int i = 0; i < 32; i += 8)
    tile[ty + i][tx] = src[(size_t)(r0 + ty + i) * C + c0 + tx];
  __syncthreads();
#pragma unroll
  for (int i = 0; i < 32; i += 8)
    dst[(size_t)(c0 + ty + i) * R + r0 + tx] = f2bf(tile[tx][ty + i]);
}

// ---------------- stable compaction: rgb tokens first, expr at 128-aligned base
__global__ __launch_bounds__(256) void compact_kernel(
    const int* __restrict__ mask, int* __restrict__ perm, int* __restrict__ counts) {
  const int NT = 256, CH = NTOK / NT;  // 64 per thread
  __shared__ int sm[NTOK];
  __shared__ int wsum[4];
  const int t = threadIdx.x;
  const int ln = t & 63, wv = t >> 6;
  for (int i = t; i < NTOK; i += NT) sm[i] = mask[i];       // coalesced
  for (int i = t; i < MPAD; i += NT) perm[i] = -1;          // gaps stay -1
  __syncthreads();
  const int base = t * CH;
  int cnt = 0;
  for (int i = 0; i < CH; ++i) cnt += (sm[base + i] != 0);
  int sc = cnt;
#pragma unroll
  for (int o = 1; o < 64; o <<= 1) {
    int u = __shfl_up(sc, o, 64);
    if (ln >= o) sc += u;
  }
  if (ln == 63) wsum[wv] = sc;
  __syncthreads();
  int woff = 0;
#pragma unroll
  for (int j = 0; j < 4; ++j) woff += (j < wv) ? wsum[j] : 0;
  const int total1 = wsum[0] + wsum[1] + wsum[2] + wsum[3];
  if (t == 0) { counts[0] = total1; counts[1] = NTOK - total1; }
  const int excl = woff + sc - cnt;  // rgb tokens before this chunk
  const int expr_base = ((total1 + 127) >> 7) << 7;
  int p1 = excl;
  int p0 = expr_base + (base - excl);
  for (int i = 0; i < CH; ++i) {
    const int idx = base + i;
    if (sm[idx] != 0) perm[p1++] = idx; else perm[p0++] = idx;
  }
}

// ---------------- LayerNorm into compacted bf16 rows ----------------
__global__ __launch_bounds__(256) void ln_kernel(
    const float* __restrict__ x, const int* __restrict__ mask,
    const int* __restrict__ perm,
    const float* __restrict__ g_rgb, const float* __restrict__ b_rgb,
    const float* __restrict__ g_expr, const float* __restrict__ b_expr,
    unsigned short* __restrict__ xln) {
  const int i = blockIdx.x;
  const int t = perm[i];
  if (t < 0) return;
  const int tid = threadIdx.x;
  const float4 v = ((const float4*)(x + (size_t)t * D_))[tid];
  float s = v.x + v.y + v.z + v.w;
  float ss = v.x * v.x + v.y * v.y + v.z * v.z + v.w * v.w;
#pragma unroll
  for (int o = 32; o > 0; o >>= 1) {
    s += __shfl_xor(s, o, 64);
    ss += __shfl_xor(ss, o, 64);
  }
  __shared__ float red[8];
  const int wv = tid >> 6, ln = tid & 63;
  if (ln == 0) { red[wv] = s; red[4 + wv] = ss; }
  __syncthreads();
  s = red[0] + red[1] + red[2] + red[3];
  ss = red[4] + red[5] + red[6] + red[7];
  const float mu = s * (1.0f / D_);
  const float var = ss * (1.0f / D_) - mu * mu;
  const float rs = rsqrtf(var + 1e-5f);
  const bool rgb = mask[t] != 0;
  const float4 gv = ((const float4*)(rgb ? g_rgb : g_expr))[tid];
  const float4 bv = ((const float4*)(rgb ? b_rgb : b_expr))[tid];
  const unsigned short o0 = f2bf((v.x - mu) * rs * gv.x + bv.x);
  const unsigned short o1 = f2bf((v.y - mu) * rs * gv.y + bv.y);
  const unsigned short o2 = f2bf((v.z - mu) * rs * gv.z + bv.z);
  const unsigned short o3 = f2bf((v.w - mu) * rs * gv.w + bv.w);
  uint2 pk;
  pk.x = (unsigned)o0 | ((unsigned)o1 << 16);
  pk.y = (unsigned)o2 | ((unsigned)o3 << 16);
  *((uint2*)(xln + (size_t)i * D_ + tid * 4)) = pk;
}

// ---------------- m97-style 128x128x(BK=64) bf16 GEMM, B^T layout ----------------
// LDS XOR-swizzled at 16B-chunk granularity (round 3: bank conflicts -> 0).
// Round 5: all swizzled LDS fragment pointers (16) and global staging pointers
// (8, advanced by +BK per iter) hoisted out of the K-loop — round 4 showed
// VALUBusy 53% from re-computed xor/shift address math.
// XCD-compact block mapping (round 4): xcd = id&7 owns a contiguous m-band.
// EP==0: C = gelu(A*W + bias) -> bf16 h[row*N + col]         (compact rows)
// EP==1: C = A*W + bias       -> fp32 out[perm[row]*N + col] (scatter, fp16-rounded)
template <int EP, int K, int N>
__global__ __launch_bounds__(256) void gemm_kernel(
    const unsigned short* __restrict__ A,       // MPAD x K, bf16 bits
    const unsigned short* __restrict__ Wt_rgb,  // N x K, bf16 bits
    const unsigned short* __restrict__ Wt_expr, // N x K
    const float* __restrict__ bias_rgb,
    const float* __restrict__ bias_expr,
    const int* __restrict__ counts,
    const int* __restrict__ perm,
    void* __restrict__ OutP) {
  constexpr int BM = 128, BN = 128, BK = 64;
  constexpr int MT = MPAD / BM;   // 129
  constexpr int NT = N / BN;      // 32 (gemm1) / 8 (gemm2)
  const int tid = threadIdx.x;
  const int id = blockIdx.x;
  const int xcd = id & 7;
  const int slot = id >> 3;
  const int p = xcd * ((MT * NT) / 8) + slot;
  const int m0 = (p / NT) * BM;
  const int n0 = (p % NT) * BN;
  const int cnt_rgb = counts[0];
  const unsigned short* Wt = (m0 < cnt_rgb) ? Wt_rgb : Wt_expr;
  const float* bias = (m0 < cnt_rgb) ? bias_rgb : bias_expr;

  __shared__ unsigned short As[BM * BK];  // swizzled [m][k]
  __shared__ unsigned short Bs[BN * BK];  // swizzled [n][k]

  f32x4 acc[4][4] = {};

  const int lane = tid & 63, wave = tid >> 6;
  const int wm = (wave & 1) * 64, wn = (wave >> 1) * 64;
  const int quad = lane >> 4, l16 = lane & 15;

  // hoisted staging pointers (advance by BK per k-iter) and LDS dests
  const unsigned short* ag[4];
  const unsigned short* bg[4];
  char* al[4];
  char* bl[4];
#pragma unroll
  for (int it = 0; it < 4; ++it) {
    const int s = it * 256 + tid;
    const int row = s >> 3;
    const int ks = ((s ^ row) & 7) * 8;  // chunk col (s&7) holds global chunk (s^row)&7
    ag[it] = A + (size_t)(m0 + row) * K + ks;
    bg[it] = Wt + (size_t)(n0 + row) * K + ks;
    al[it] = (char*)As + s * 16;
    bl[it] = (char*)Bs + s * 16;
  }
  // hoisted swizzled fragment pointers: k0-invariant (2 kk-phases x 4 frags)
  const unsigned short* ap[2][4];
  const unsigned short* bp[2][4];
#pragma unroll
  for (int hh = 0; hh < 2; ++hh) {
    const int cb = hh * 4 + quad;
#pragma unroll
    for (int mi = 0; mi < 4; ++mi) {
      const int row = wm + mi * 16 + l16;
      ap[hh][mi] = As + row * BK + (((cb ^ row) & 7) << 3);
    }
#pragma unroll
    for (int ni = 0; ni < 4; ++ni) {
      const int row = wn + ni * 16 + l16;
      bp[hh][ni] = Bs + row * BK + (((cb ^ row) & 7) << 3);
    }
  }

  for (int k0 = 0; k0 < K; k0 += BK) {
#pragma unroll
    for (int it = 0; it < 4; ++it) {
      gld16(ag[it], al[it]);
      gld16(bg[it], bl[it]);
      ag[it] += BK;
      bg[it] += BK;
    }
    __syncthreads();
#pragma unroll
    for (int hh = 0; hh < 2; ++hh) {
      bf16x8 a[4], b[4];
#pragma unroll
      for (int mi = 0; mi < 4; ++mi) a[mi] = *(const bf16x8*)ap[hh][mi];
#pragma unroll
      for (int ni = 0; ni < 4; ++ni) b[ni] = *(const bf16x8*)bp[hh][ni];
#pragma unroll
      for (int mi = 0; mi < 4; ++mi)
#pragma unroll
        for (int ni = 0; ni < 4; ++ni)
          acc[mi][ni] = __builtin_amdgcn_mfma_f32_16x16x32_bf16(a[mi], b[ni], acc[mi][ni], 0, 0, 0);
    }
    __syncthreads();
  }

  // epilogue: C/D layout col = lane&15, row = quad*4 + r  [m89/m91-verified]
  float bv[4];
#pragma unroll
  for (int ni = 0; ni < 4; ++ni) bv[ni] = bias[n0 + wn + ni * 16 + l16];

#pragma unroll
  for (int mi = 0; mi < 4; ++mi) {
#pragma unroll
    for (int r = 0; r < 4; ++r) {
      const int row = m0 + wm + mi * 16 + quad * 4 + r;
      if (EP == 0) {
        // gap rows read poisoned-but-finite xln; store unconditionally (never scattered)
        unsigned short* orow = (unsigned short*)OutP + (size_t)row * N + n0 + wn + l16;
#pragma unroll
        for (int ni = 0; ni < 4; ++ni) {
          orow[ni * 16] = f2bf(gelu_fast(acc[mi][ni][r] + bv[ni]));
        }
      } else {
        const int p2 = perm[row];
        if (p2 < 0) continue;
        // reference output is z.astype(float16); d_out is an fp32 buffer
        float* orow = (float*)OutP + (size_t)p2 * N + n0 + wn + l16;
#pragma unroll
        for (int ni = 0; ni < 4; ++ni) {
          float v = acc[mi][ni][r] + bv[ni];
          orow[ni * 16] = __half2float(__float2half_rn(v));
        }
      }
    }
  }
}

extern "C" void kernel_launch(void* const* d_in, const int* in_sizes, int n_in,
                              void* d_out, int out_size, void* d_ws, size_t ws_size,
                              hipStream_t stream) {
  const float* x       = (const float*)d_in[0];
  const int*   mask    = (const int*)d_in[1];
  const float* g_rgb   = (const float*)d_in[2];
  const float* b_rgb   = (const float*)d_in[3];
  const float* w1_rgb  = (const float*)d_in[4];
  const float* b1_rgb  = (const float*)d_in[5];
  const float* w2_rgb  = (const float*)d_in[6];
  const float* b2_rgb  = (const float*)d_in[7];
  const float* g_expr  = (const float*)d_in[8];
  const float* b_expr  = (const float*)d_in[9];
  const float* w1_expr = (const float*)d_in[10];
  const float* b1_expr = (const float*)d_in[11];
  const float* w2_expr = (const float*)d_in[12];
  const float* b2_expr = (const float*)d_in[13];

  char* w = (char*)d_ws;
  int* counts               = (int*)(w + 0);
  int* perm                 = (int*)(w + 256);
  unsigned short* w1t_rgb   = (unsigned short*)(w + 66560);
  unsigned short* w1t_expr  = (unsigned short*)(w + 8455168);
  unsigned short* w2t_rgb   = (unsigned short*)(w + 16843776);
  unsigned short* w2t_expr  = (unsigned short*)(w + 25232384);
  unsigned short* xln       = (unsigned short*)(w + 33620992);  // MPAD x 1024 bf16
  unsigned short* h         = (unsigned short*)(w + 67437568);  // MPAD x 4096 bf16
  // total ws use: 202,703,872 bytes

  // 1) stable expert compaction
  compact_kernel<<<1, 256, 0, stream>>>(mask, perm, counts);

  // 2) weight transpose+convert (all 4 in one launch): W (KxN fp32) -> Wt (NxK bf16)
  transpose4_kernel<<<16384, 256, 0, stream>>>(
      w1_rgb, w1_expr, w2_rgb, w2_expr, w1t_rgb, w1t_expr, w2t_rgb, w2t_expr);

  // 3) LayerNorm into compacted rows
  ln_kernel<<<MPAD, 256, 0, stream>>>(x, mask, perm, g_rgb, b_rgb, g_expr, b_expr, xln);

  // 4) h = gelu(xln @ w1 + b1)   (M=MPAD, K=1024, N=4096)
  gemm_kernel<0, D_, H_><<<dim3((H_ / 128) * (MPAD / 128)), 256, 0, stream>>>(
      xln, w1t_rgb, w1t_expr, b1_rgb, b1_expr, counts, perm, h);

  // 5) out[tok] = h @ w2 + b2    (M=MPAD, K=4096, N=1024), scatter via perm, fp32 out
  gemm_kernel<1, H_, D_><<<dim3((D_ / 128) * (MPAD / 128)), 256, 0, stream>>>(
      h, w2t_rgb, w2t_expr, b2_rgb, b2_expr, counts, perm, d_out);
}